// Round 3
// baseline (100.430 us; speedup 1.0000x reference)
//
#include <hip/hip_runtime.h>
#include <hip/hip_fp16.h>

typedef _Float16 f16x8 __attribute__((ext_vector_type(8)));
typedef float    f32x4 __attribute__((ext_vector_type(4)));

#define BM 128

// layer geometry (h=0 => only first IN rows of each weight matter)
#define IN0 74
#define H0  269
#define H1  179
#define H2  64
#define KS0 3     // ceil(IN0/32) k-steps
#define KS1 9     // ceil(H0/32)
#define KS2 6     // ceil(H1/32)
#define NP0 272   // H0 padded to mult of 16
#define NP1 192   // H1 padded
#define NP2 64
#define PX  104   // LDS row pitch (halfs); pitch/2 % 8 == 4 -> 2-way banks on b128
#define PH0 296
#define PH1 200

__device__ __forceinline__ float fsigm(float z) {
  return __builtin_amdgcn_rcpf(1.f + __expf(-z));
}
__device__ __forceinline__ float ftanh(float v) {
  return 1.f - 2.f * __builtin_amdgcn_rcpf(1.f + __expf(2.f * v));
}

// One CfC layer for this block's 128 rows. 16 waves iterate a flat work-unit
// space u = (tile t, row-half wm): u>>1 = t, u&1 = wm. Weights packed in
// fragment-major 1KB chunks (chunk c = (t*KS+ks)*4+m, lane*8 halfs) so each
// B load is one coalesced global_load_dwordx4.
template<int KS, int NP, int HID, int IPITCH, int OPITCH, bool LAST>
__device__ __forceinline__ void layer_run(
    const _Float16* in_lds, _Float16* out_lds, float* out_g,
    const _Float16* __restrict__ wt, const float4* __restrict__ pb,
    int lane, int wid)
{
  const int l15 = lane & 15;
  const int lg  = lane >> 4;
  constexpr int NT = NP / 16;
  for (int u = wid; u < NT * 2; u += 16) {
    const int t  = u >> 1;
    const int mbase = (u & 1) * 64;
    const int n0 = t * 16 + l15;
    f32x4 acc[4][4] = {};
    const _Float16* wb = wt + (size_t)(t * KS * 4) * 512 + lane * 8;
    #pragma unroll
    for (int ks = 0; ks < KS; ++ks) {
      const int k0 = ks * 32;
      f16x8 a[4], b[4];
      #pragma unroll
      for (int m = 0; m < 4; ++m)
        b[m] = *(const f16x8*)(wb + (size_t)(ks * 4 + m) * 512);
      #pragma unroll
      for (int s = 0; s < 4; ++s)
        a[s] = *(const f16x8*)(in_lds + (mbase + s * 16 + l15) * IPITCH + k0 + lg * 8);
      #pragma unroll
      for (int m = 0; m < 4; ++m)
        #pragma unroll
        for (int s = 0; s < 4; ++s)
          acc[m][s] = __builtin_amdgcn_mfma_f32_16x16x32_f16(a[s], b[m], acc[m][s], 0, 0, 0);
    }
    const float4 bias = pb[t * 16 + l15];
    #pragma unroll
    for (int s = 0; s < 4; ++s) {
      #pragma unroll
      for (int q = 0; q < 4; ++q) {
        float f1 = acc[0][s][q] + bias.x;
        float f2 = acc[1][s][q] + bias.y;
        float ta = acc[2][s][q] + bias.z;
        float tb = acc[3][s][q] + bias.w;
        float th1 = ftanh(f1);
        float th2 = ftanh(f2);
        float ti  = fsigm(tb - ta);
        float o   = th1 + ti * (th2 - th1);
        if (n0 < HID) {
          const int row = mbase + s * 16 + lg * 4 + q;
          if (LAST) out_g[row * 64 + n0] = o;
          else      out_lds[row * OPITCH + n0] = (_Float16)o;
        }
      }
    }
  }
}

__global__ __launch_bounds__(1024, 4) void cfc_fused(
    const float* __restrict__ x,
    const _Float16* __restrict__ wt0, const _Float16* __restrict__ wt1,
    const _Float16* __restrict__ wt2,
    const float4* __restrict__ pb0, const float4* __restrict__ pb1,
    const float4* __restrict__ pb2,
    float* __restrict__ out)
{
  __shared__ __align__(16) _Float16 xs [BM * PX];
  __shared__ __align__(16) _Float16 h0s[BM * PH0];
  __shared__ __align__(16) _Float16 h1s[BM * PH1];
  const int tid  = threadIdx.x;
  const int lane = tid & 63;
  const int wid  = tid >> 6;
  const int m0 = blockIdx.x * BM;

  // zero ONLY the K-pad columns each MFMA actually reads:
  // xs cols [74,96), h0s cols [269,288), h1s cols [179,192)
  for (int i = tid; i < BM * 22; i += 1024) { int r = i / 22; xs [r * PX  + IN0 + i - r * 22] = (_Float16)0.f; }
  for (int i = tid; i < BM * 19; i += 1024) { int r = i / 19; h0s[r * PH0 + H0  + i - r * 19] = (_Float16)0.f; }
  for (int i = tid; i < BM * 13; i += 1024) { int r = i / 13; h1s[r * PH1 + H1  + i - r * 13] = (_Float16)0.f; }

  // stage x (fp32 -> fp16) into LDS, float2-vectorized (74 = 37 float2/row)
  for (int i = tid; i < BM * 37; i += 1024) {
    int r = i / 37, p = i - r * 37;
    float2 v = ((const float2*)x)[(size_t)(m0 + r) * 37 + p];
    xs[r * PX + 2 * p]     = (_Float16)v.x;
    xs[r * PX + 2 * p + 1] = (_Float16)v.y;
  }
  __syncthreads();

  layer_run<KS0, NP0, H0, PX,  PH0, false>(xs,  h0s, nullptr, wt0, pb0, lane, wid);
  __syncthreads();
  layer_run<KS1, NP1, H1, PH0, PH1, false>(h0s, h1s, nullptr, wt1, pb1, lane, wid);
  __syncthreads();
  layer_run<KS2, NP2, H2, PH1, 1,   true >(h1s, nullptr, out + (size_t)m0 * 64,
                                           wt2, pb2, lane, wid);
}

// Pack weights into fragment-major order. One thread per (chunk, lane):
// wt[idx*8 + j] = W_m[ks*32 + (lane>>4)*8 + j][t*16 + (lane&15)] (masked,
// zero outside IN x HID).
__global__ void pack_w(const float* __restrict__ wf1, const float* __restrict__ wf2,
                       const float* __restrict__ wta, const float* __restrict__ wtb,
                       const int* __restrict__ mask, _Float16* __restrict__ wt,
                       int IN, int HID, int KS, int NT)
{
  int idx = blockIdx.x * 256 + threadIdx.x;
  int total = NT * KS * 4 * 64;
  if (idx >= total) return;
  int lane = idx & 63;
  int c = idx >> 6;          // chunk = (t*KS + ks)*4 + m
  int m = c & 3;
  int tk = c >> 2;
  int ks = tk % KS;
  int t  = tk / KS;
  int n  = t * 16 + (lane & 15);
  int k0 = ks * 32 + (lane >> 4) * 8;
  const float* w = (m == 0) ? wf1 : (m == 1) ? wf2 : (m == 2) ? wta : wtb;
  f16x8 v = {};
  if (n < HID) {
    #pragma unroll
    for (int j = 0; j < 8; ++j) {
      int k = k0 + j;
      float f = 0.f;
      if (k < IN) {
        f = w[k * HID + n];
        if (m < 2) f *= (float)mask[k * HID + n];
      }
      v[j] = (_Float16)f;
    }
  }
  *(f16x8*)(wt + (size_t)idx * 8) = v;
}

__global__ void pack_b(const float* __restrict__ b1, const float* __restrict__ b2,
                       const float* __restrict__ b3, const float* __restrict__ b4,
                       float4* __restrict__ pb, int HID, int NP)
{
  int j = blockIdx.x * 256 + threadIdx.x;
  if (j >= NP) return;
  float4 v = make_float4(0.f, 0.f, 0.f, 0.f);
  if (j < HID) v = make_float4(b1[j], b2[j], b3[j], b4[j]);
  pb[j] = v;
}

extern "C" void kernel_launch(void* const* d_in, const int* in_sizes, int n_in,
                              void* d_out, int out_size, void* d_ws, size_t ws_size,
                              hipStream_t stream)
{
  const float* x = (const float*)d_in[0];
  const float* Wf1_0 = (const float*)d_in[1];
  const float* bf1_0 = (const float*)d_in[2];
  const float* Wf2_0 = (const float*)d_in[3];
  const float* bf2_0 = (const float*)d_in[4];
  const float* Wta_0 = (const float*)d_in[5];
  const float* bta_0 = (const float*)d_in[6];
  const float* Wtb_0 = (const float*)d_in[7];
  const float* btb_0 = (const float*)d_in[8];
  const int*   msk_0 = (const int*)  d_in[9];
  const float* Wf1_1 = (const float*)d_in[10];
  const float* bf1_1 = (const float*)d_in[11];
  const float* Wf2_1 = (const float*)d_in[12];
  const float* bf2_1 = (const float*)d_in[13];
  const float* Wta_1 = (const float*)d_in[14];
  const float* bta_1 = (const float*)d_in[15];
  const float* Wtb_1 = (const float*)d_in[16];
  const float* btb_1 = (const float*)d_in[17];
  const int*   msk_1 = (const int*)  d_in[18];
  const float* Wf1_2 = (const float*)d_in[19];
  const float* bf1_2 = (const float*)d_in[20];
  const float* Wf2_2 = (const float*)d_in[21];
  const float* bf2_2 = (const float*)d_in[22];
  const float* Wta_2 = (const float*)d_in[23];
  const float* bta_2 = (const float*)d_in[24];
  const float* Wtb_2 = (const float*)d_in[25];
  const float* btb_2 = (const float*)d_in[26];
  const int*   msk_2 = (const int*)  d_in[27];

  char* ws = (char*)d_ws;
  _Float16* wt0 = (_Float16*)(ws + 0);        // 17*3*4*1024 = 208896
  _Float16* wt1 = (_Float16*)(ws + 208896);   // 12*9*4*1024 = 442368
  _Float16* wt2 = (_Float16*)(ws + 651264);   //  4*6*4*1024 =  98304
  float4*   pb0 = (float4*)  (ws + 749568);   // 272*16 = 4352
  float4*   pb1 = (float4*)  (ws + 753920);   // 192*16 = 3072
  float4*   pb2 = (float4*)  (ws + 756992);   // 64*16  = 1024

  pack_w<<<(17 * KS0 * 4 * 64 + 255) / 256, 256, 0, stream>>>(
      Wf1_0, Wf2_0, Wta_0, Wtb_0, msk_0, wt0, IN0, H0, KS0, 17);
  pack_w<<<(12 * KS1 * 4 * 64 + 255) / 256, 256, 0, stream>>>(
      Wf1_1, Wf2_1, Wta_1, Wtb_1, msk_1, wt1, H0, H1, KS1, 12);
  pack_w<<<( 4 * KS2 * 4 * 64 + 255) / 256, 256, 0, stream>>>(
      Wf1_2, Wf2_2, Wta_2, Wtb_2, msk_2, wt2, H1, H2, KS2, 4);
  pack_b<<<(NP0 + 255) / 256, 256, 0, stream>>>(bf1_0, bf2_0, bta_0, btb_0, pb0, H0, NP0);
  pack_b<<<1, 256, 0, stream>>>(bf1_1, bf2_1, bta_1, btb_1, pb1, H1, NP1);
  pack_b<<<1, 256, 0, stream>>>(bf1_2, bf2_2, bta_2, btb_2, pb2, H2, NP2);

  cfc_fused<<<65536 / BM, 1024, 0, stream>>>(x, wt0, wt1, wt2, pb0, pb1, pb2,
                                             (float*)d_out);
}

// Round 4
// 91.920 us; speedup vs baseline: 1.0926x; 1.0926x over previous
//
#include <hip/hip_runtime.h>
#include <hip/hip_fp16.h>

typedef _Float16 f16x8 __attribute__((ext_vector_type(8)));
typedef float    f32x4 __attribute__((ext_vector_type(4)));

#define BM 128

// layer geometry (h=0 => only first IN rows of each weight matter)
#define IN0 74
#define H0  269
#define H1  179
#define H2  64
#define KS0 3     // ceil((IN0+1)/32) k-steps (includes bias row at k=IN)
#define KS1 9
#define KS2 6
#define NP0 272   // H0 padded to mult of 16
#define NP1 192
#define NP2 64
#define PX  104   // LDS row pitch (halfs); stride mod banks -> <=2-way conflict
#define PH0 296
#define PH1 200

__device__ __forceinline__ float fsigm(float z) {
  return __builtin_amdgcn_rcpf(1.f + __expf(-z));
}
__device__ __forceinline__ float ftanh(float v) {
  return 1.f - 2.f * __builtin_amdgcn_rcpf(1.f + __expf(2.f * v));
}

// One 2-matrix K-sweep. wb points at (tile t, mat mp, lane)-offset packed
// weights; consecutive mats are 512-half chunks apart, consecutive ks 4*512.
template<int KS, int S, int IPITCH>
__device__ __forceinline__ void kloop(f32x4 (&acc)[2][S],
    const _Float16* __restrict__ wb, const _Float16* a_base)
{
  #pragma unroll
  for (int ks = 0; ks < KS; ++ks) {
    f16x8 b0 = *(const f16x8*)(wb + (size_t)(ks * 4    ) * 512);
    f16x8 b1 = *(const f16x8*)(wb + (size_t)(ks * 4 + 1) * 512);
    #pragma unroll
    for (int s = 0; s < S; ++s) {
      f16x8 a = *(const f16x8*)(a_base + s * 16 * IPITCH + ks * 32);
      acc[0][s] = __builtin_amdgcn_mfma_f32_16x16x32_f16(a, b0, acc[0][s], 0, 0, 0);
      acc[1][s] = __builtin_amdgcn_mfma_f32_16x16x32_f16(a, b1, acc[1][s], 0, 0, 0);
    }
  }
}

// One CfC layer for this block's 128 rows. 16 waves iterate flat work-units
// u = (tile t, row-group g of 128/G rows). Per u: sweep K for (ta,tb),
// convert to ti = sigmoid(tb-ta) (frees accs), sweep K for (ff1,ff2),
// combine o = th1 + ti*(th2-th1). Bias comes in via the k=IN one-hot row.
template<int KS, int NP, int HID, int IPITCH, int OPITCH, bool LAST, int G>
__device__ __forceinline__ void layer_run(
    const _Float16* in_lds, _Float16* out_lds, float* out_g,
    const _Float16* __restrict__ wt, int lane, int wid)
{
  constexpr int S = 8 / G;          // 16-row subtiles per unit
  constexpr int NT = NP / 16;
  const int l15 = lane & 15;
  const int lg  = lane >> 4;
  for (int u = wid; u < NT * G; u += 16) {
    const int t = u / G;
    const int mbase = (u % G) * (S * 16);
    const int n0 = t * 16 + l15;
    const _Float16* a_base = in_lds + (mbase + l15) * IPITCH + lg * 8;
    const _Float16* wtt = wt + (size_t)(t * KS * 4) * 512 + lane * 8;

    f32x4 acc[2][S] = {};
    kloop<KS, S, IPITCH>(acc, wtt + 2 * 512, a_base);   // mats 2,3 = ta,tb
    float ti[S][4];
    #pragma unroll
    for (int s = 0; s < S; ++s)
      #pragma unroll
      for (int q = 0; q < 4; ++q)
        ti[s][q] = fsigm(acc[1][s][q] - acc[0][s][q]);

    #pragma unroll
    for (int s = 0; s < S; ++s) {
      f32x4 z = {0.f, 0.f, 0.f, 0.f};
      acc[0][s] = z; acc[1][s] = z;
    }
    kloop<KS, S, IPITCH>(acc, wtt, a_base);             // mats 0,1 = ff1,ff2

    #pragma unroll
    for (int s = 0; s < S; ++s) {
      #pragma unroll
      for (int q = 0; q < 4; ++q) {
        float th1 = ftanh(acc[0][s][q]);
        float th2 = ftanh(acc[1][s][q]);
        float o   = th1 + ti[s][q] * (th2 - th1);
        const int row = mbase + s * 16 + lg * 4 + q;
        if (LAST) {
          out_g[row * 64 + n0] = o;        // NP2 == H2, no guard needed
        } else if (n0 < HID) {
          out_lds[row * OPITCH + n0] = (_Float16)o;
        }
      }
    }
  }
}

__global__ __launch_bounds__(1024, 4) void cfc_fused(
    const float* __restrict__ x,
    const _Float16* __restrict__ wt0, const _Float16* __restrict__ wt1,
    const _Float16* __restrict__ wt2,
    float* __restrict__ out)
{
  __shared__ __align__(16) _Float16 xs [BM * PX];
  __shared__ __align__(16) _Float16 h0s[BM * PH0];
  __shared__ __align__(16) _Float16 h1s[BM * PH1];
  const int tid  = threadIdx.x;
  const int lane = tid & 63;
  const int wid  = tid >> 6;
  const int m0 = blockIdx.x * BM;

  // pad columns: 1.0 at the bias slot k==IN, 0 elsewhere in [IN, KP)
  for (int i = tid; i < BM * 22; i += 1024) { int r = i / 22, c = IN0 + i - r * 22; xs [r * PX  + c] = (_Float16)(c == IN0 ? 1.f : 0.f); }
  for (int i = tid; i < BM * 19; i += 1024) { int r = i / 19, c = H0  + i - r * 19; h0s[r * PH0 + c] = (_Float16)(c == H0  ? 1.f : 0.f); }
  for (int i = tid; i < BM * 13; i += 1024) { int r = i / 13, c = H1  + i - r * 13; h1s[r * PH1 + c] = (_Float16)(c == H1  ? 1.f : 0.f); }

  // stage x (fp32 -> fp16) into LDS, float2-vectorized (74 = 37 float2/row)
  for (int i = tid; i < BM * 37; i += 1024) {
    int r = i / 37, p = i - r * 37;
    float2 v = ((const float2*)x)[(size_t)(m0 + r) * 37 + p];
    xs[r * PX + 2 * p]     = (_Float16)v.x;
    xs[r * PX + 2 * p + 1] = (_Float16)v.y;
  }
  __syncthreads();

  layer_run<KS0, NP0, H0, PX,  PH0, false, 2>(xs,  h0s, nullptr, wt0, lane, wid);
  __syncthreads();
  layer_run<KS1, NP1, H1, PH0, PH1, false, 2>(h0s, h1s, nullptr, wt1, lane, wid);
  __syncthreads();
  layer_run<KS2, NP2, H2, PH1, 1,   true,  4>(h1s, nullptr, out + (size_t)m0 * 64,
                                              wt2, lane, wid);
}

// Pack weights into fragment-major order. One thread per (chunk, lane):
// wt[idx*8 + j] = W_m[k][n] for k = ks*32+(lane>>4)*8+j, n = t*16+(lane&15),
// masked for ff mats; row k==IN carries the bias vector; zero elsewhere.
__global__ void pack_w(const float* __restrict__ wf1, const float* __restrict__ wf2,
                       const float* __restrict__ wta, const float* __restrict__ wtb,
                       const float* __restrict__ bf1, const float* __restrict__ bf2,
                       const float* __restrict__ bta, const float* __restrict__ btb,
                       const int* __restrict__ mask, _Float16* __restrict__ wt,
                       int IN, int HID, int KS, int NT)
{
  int idx = blockIdx.x * 256 + threadIdx.x;
  int total = NT * KS * 4 * 64;
  if (idx >= total) return;
  int lane = idx & 63;
  int c = idx >> 6;          // chunk = (t*KS + ks)*4 + m
  int m = c & 3;
  int tk = c >> 2;
  int ks = tk % KS;
  int t  = tk / KS;
  int n  = t * 16 + (lane & 15);
  int k0 = ks * 32 + (lane >> 4) * 8;
  const float* w = (m == 0) ? wf1 : (m == 1) ? wf2 : (m == 2) ? wta : wtb;
  const float* b = (m == 0) ? bf1 : (m == 1) ? bf2 : (m == 2) ? bta : btb;
  f16x8 v = {};
  if (n < HID) {
    #pragma unroll
    for (int j = 0; j < 8; ++j) {
      int k = k0 + j;
      float f = 0.f;
      if (k < IN) {
        f = w[k * HID + n];
        if (m < 2) f *= (float)mask[k * HID + n];
      } else if (k == IN) {
        f = b[n];
      }
      v[j] = (_Float16)f;
    }
  }
  *(f16x8*)(wt + (size_t)idx * 8) = v;
}

extern "C" void kernel_launch(void* const* d_in, const int* in_sizes, int n_in,
                              void* d_out, int out_size, void* d_ws, size_t ws_size,
                              hipStream_t stream)
{
  const float* x = (const float*)d_in[0];
  const float* Wf1_0 = (const float*)d_in[1];
  const float* bf1_0 = (const float*)d_in[2];
  const float* Wf2_0 = (const float*)d_in[3];
  const float* bf2_0 = (const float*)d_in[4];
  const float* Wta_0 = (const float*)d_in[5];
  const float* bta_0 = (const float*)d_in[6];
  const float* Wtb_0 = (const float*)d_in[7];
  const float* btb_0 = (const float*)d_in[8];
  const int*   msk_0 = (const int*)  d_in[9];
  const float* Wf1_1 = (const float*)d_in[10];
  const float* bf1_1 = (const float*)d_in[11];
  const float* Wf2_1 = (const float*)d_in[12];
  const float* bf2_1 = (const float*)d_in[13];
  const float* Wta_1 = (const float*)d_in[14];
  const float* bta_1 = (const float*)d_in[15];
  const float* Wtb_1 = (const float*)d_in[16];
  const float* btb_1 = (const float*)d_in[17];
  const int*   msk_1 = (const int*)  d_in[18];
  const float* Wf1_2 = (const float*)d_in[19];
  const float* bf1_2 = (const float*)d_in[20];
  const float* Wf2_2 = (const float*)d_in[21];
  const float* bf2_2 = (const float*)d_in[22];
  const float* Wta_2 = (const float*)d_in[23];
  const float* bta_2 = (const float*)d_in[24];
  const float* Wtb_2 = (const float*)d_in[25];
  const float* btb_2 = (const float*)d_in[26];
  const int*   msk_2 = (const int*)  d_in[27];

  char* ws = (char*)d_ws;
  _Float16* wt0 = (_Float16*)(ws + 0);        // 17*3*4*1024 = 208896
  _Float16* wt1 = (_Float16*)(ws + 208896);   // 12*9*4*1024 = 442368
  _Float16* wt2 = (_Float16*)(ws + 651264);   //  4*6*4*1024 =  98304

  pack_w<<<(17 * KS0 * 4 * 64 + 255) / 256, 256, 0, stream>>>(
      Wf1_0, Wf2_0, Wta_0, Wtb_0, bf1_0, bf2_0, bta_0, btb_0, msk_0, wt0, IN0, H0, KS0, 17);
  pack_w<<<(12 * KS1 * 4 * 64 + 255) / 256, 256, 0, stream>>>(
      Wf1_1, Wf2_1, Wta_1, Wtb_1, bf1_1, bf2_1, bta_1, btb_1, msk_1, wt1, H0, H1, KS1, 12);
  pack_w<<<( 4 * KS2 * 4 * 64 + 255) / 256, 256, 0, stream>>>(
      Wf1_2, Wf2_2, Wta_2, Wtb_2, bf1_2, bf2_2, bta_2, btb_2, msk_2, wt2, H1, H2, KS2, 4);

  cfc_fused<<<65536 / BM, 1024, 0, stream>>>(x, wt0, wt1, wt2, (float*)d_out);
}

// Round 5
// 83.678 us; speedup vs baseline: 1.2002x; 1.0985x over previous
//
#include <hip/hip_runtime.h>
#include <hip/hip_fp16.h>

typedef _Float16 f16x8 __attribute__((ext_vector_type(8)));
typedef float    f32x4 __attribute__((ext_vector_type(4)));

#define BM 128

// layer geometry (h=0 => only first IN rows of each weight matter; the
// padded K range includes a bias row at k==IN carrying 1.0 in activations)
#define IN0 74
#define H0  269
#define H1  179
#define H2  64
#define KS0 3     // ceil((IN0+1)/32)
#define KS1 9     // ceil((H0+1)/32)
#define KS2 6     // ceil((H1+1)/32)
#define NP0 272
#define NP1 192
#define NP2 64
#define PX  104   // LDS row pitches (halfs): all give <=2-way b128 bank groups
#define PH0 296
#define PH1 200

__device__ __forceinline__ float fsigm(float z) {
  return __builtin_amdgcn_rcpf(1.f + __expf(-z));
}
__device__ __forceinline__ float ftanh(float v) {
  return 1.f - 2.f * __builtin_amdgcn_rcpf(1.f + __expf(2.f * v));
}

// One 2-matrix K-sweep with the WHOLE B operand preloaded to registers first
// (one batched L2 round-trip), then a pure {ds_read A -> MFMA} stream.
template<int KS, int S, int IPITCH, int MOFF>
__device__ __forceinline__ void sweep(f32x4 (&acc)[2][S],
    const _Float16* __restrict__ wb, const _Float16* a_base)
{
  f16x8 b[KS][2];
  #pragma unroll
  for (int ks = 0; ks < KS; ++ks) {
    b[ks][0] = *(const f16x8*)(wb + (size_t)(ks * 4 + MOFF    ) * 512);
    b[ks][1] = *(const f16x8*)(wb + (size_t)(ks * 4 + MOFF + 1) * 512);
  }
  #pragma unroll
  for (int ks = 0; ks < KS; ++ks) {
    #pragma unroll
    for (int s = 0; s < S; ++s) {
      f16x8 a = *(const f16x8*)(a_base + s * 16 * IPITCH + ks * 32);
      acc[0][s] = __builtin_amdgcn_mfma_f32_16x16x32_f16(a, b[ks][0], acc[0][s], 0, 0, 0);
      acc[1][s] = __builtin_amdgcn_mfma_f32_16x16x32_f16(a, b[ks][1], acc[1][s], 0, 0, 0);
    }
  }
}

// One CfC layer for this block's 128 rows. 8 waves iterate flat work-units
// u = (tile t = u>>1, 64-row half = u&1), S=4 subtiles each. Per unit:
// preload+sweep (ta,tb) -> ti = sigmoid(tb-ta) -> preload+sweep (ff1,ff2)
// -> o = th1 + ti*(th2-th1). Bias arrives via the k==IN one-hot column.
template<int KS, int NP, int HID, int IPITCH, int OPITCH, bool LAST>
__device__ __forceinline__ void layer_run(
    const _Float16* in_lds, _Float16* out_lds, float* out_g,
    const _Float16* __restrict__ wt, int lane, int wid)
{
  constexpr int S = 4;
  constexpr int NT = NP / 16;
  const int l15 = lane & 15;
  const int lg  = lane >> 4;
  for (int u = wid; u < NT * 2; u += 8) {
    const int t = u >> 1;
    const int mbase = (u & 1) * 64;
    const int n0 = t * 16 + l15;
    const _Float16* a_base = in_lds + (mbase + l15) * IPITCH + lg * 8;
    const _Float16* wtt = wt + (size_t)(t * KS * 4) * 512 + lane * 8;

    f32x4 acc[2][S] = {};
    sweep<KS, S, IPITCH, 2>(acc, wtt, a_base);          // mats 2,3 = ta,tb
    float ti[S][4];
    #pragma unroll
    for (int s = 0; s < S; ++s)
      #pragma unroll
      for (int q = 0; q < 4; ++q)
        ti[s][q] = fsigm(acc[1][s][q] - acc[0][s][q]);

    #pragma unroll
    for (int s = 0; s < S; ++s) {
      f32x4 z = {0.f, 0.f, 0.f, 0.f};
      acc[0][s] = z; acc[1][s] = z;
    }
    sweep<KS, S, IPITCH, 0>(acc, wtt, a_base);          // mats 0,1 = ff1,ff2

    #pragma unroll
    for (int s = 0; s < S; ++s) {
      #pragma unroll
      for (int q = 0; q < 4; ++q) {
        float th1 = ftanh(acc[0][s][q]);
        float th2 = ftanh(acc[1][s][q]);
        float o   = th1 + ti[s][q] * (th2 - th1);
        const int row = mbase + s * 16 + lg * 4 + q;
        if (LAST) {
          out_g[row * 64 + n0] = o;        // NP2 == H2, no guard needed
        } else if (n0 < HID) {
          out_lds[row * OPITCH + n0] = (_Float16)o;
        }
      }
    }
  }
}

__global__ __launch_bounds__(512, 2) void cfc_fused(
    const float* __restrict__ x,
    const _Float16* __restrict__ wt0, const _Float16* __restrict__ wt1,
    const _Float16* __restrict__ wt2,
    float* __restrict__ out)
{
  __shared__ __align__(16) _Float16 xs [BM * PX];
  __shared__ __align__(16) _Float16 h0s[BM * PH0];
  __shared__ __align__(16) _Float16 h1s[BM * PH1];
  const int tid  = threadIdx.x;
  const int lane = tid & 63;
  const int wid  = tid >> 6;
  const int m0 = blockIdx.x * BM;

  // pad columns: 1.0 at the bias slot k==IN, 0 elsewhere in [IN, KP)
  for (int i = tid; i < BM * 22; i += 512) { int r = i / 22, c = IN0 + i - r * 22; xs [r * PX  + c] = (_Float16)(c == IN0 ? 1.f : 0.f); }
  for (int i = tid; i < BM * 19; i += 512) { int r = i / 19, c = H0  + i - r * 19; h0s[r * PH0 + c] = (_Float16)(c == H0  ? 1.f : 0.f); }
  for (int i = tid; i < BM * 13; i += 512) { int r = i / 13, c = H1  + i - r * 13; h1s[r * PH1 + c] = (_Float16)(c == H1  ? 1.f : 0.f); }

  // stage x (fp32 -> fp16) into LDS, float2-vectorized (74 = 37 float2/row)
  for (int i = tid; i < BM * 37; i += 512) {
    int r = i / 37, p = i - r * 37;
    float2 v = ((const float2*)x)[(size_t)(m0 + r) * 37 + p];
    xs[r * PX + 2 * p]     = (_Float16)v.x;
    xs[r * PX + 2 * p + 1] = (_Float16)v.y;
  }
  __syncthreads();

  layer_run<KS0, NP0, H0, PX,  PH0, false>(xs,  h0s, nullptr, wt0, lane, wid);
  __syncthreads();
  layer_run<KS1, NP1, H1, PH0, PH1, false>(h0s, h1s, nullptr, wt1, lane, wid);
  __syncthreads();
  layer_run<KS2, NP2, H2, PH1, 1,   true >(h1s, nullptr, out + (size_t)m0 * 64,
                                           wt2, lane, wid);
}

// Pack weights into fragment-major order. One thread per (chunk, lane):
// wt[idx*8 + j] = W_m[k][n] for k = ks*32+(lane>>4)*8+j, n = t*16+(lane&15),
// masked for ff mats; row k==IN carries the bias vector; zero elsewhere.
__global__ void pack_w(const float* __restrict__ wf1, const float* __restrict__ wf2,
                       const float* __restrict__ wta, const float* __restrict__ wtb,
                       const float* __restrict__ bf1, const float* __restrict__ bf2,
                       const float* __restrict__ bta, const float* __restrict__ btb,
                       const int* __restrict__ mask, _Float16* __restrict__ wt,
                       int IN, int HID, int KS, int NT)
{
  int idx = blockIdx.x * 256 + threadIdx.x;
  int total = NT * KS * 4 * 64;
  if (idx >= total) return;
  int lane = idx & 63;
  int c = idx >> 6;          // chunk = (t*KS + ks)*4 + m
  int m = c & 3;
  int tk = c >> 2;
  int ks = tk % KS;
  int t  = tk / KS;
  int n  = t * 16 + (lane & 15);
  int k0 = ks * 32 + (lane >> 4) * 8;
  const float* w = (m == 0) ? wf1 : (m == 1) ? wf2 : (m == 2) ? wta : wtb;
  const float* b = (m == 0) ? bf1 : (m == 1) ? bf2 : (m == 2) ? bta : btb;
  f16x8 v = {};
  if (n < HID) {
    #pragma unroll
    for (int j = 0; j < 8; ++j) {
      int k = k0 + j;
      float f = 0.f;
      if (k < IN) {
        f = w[k * HID + n];
        if (m < 2) f *= (float)mask[k * HID + n];
      } else if (k == IN) {
        f = b[n];
      }
      v[j] = (_Float16)f;
    }
  }
  *(f16x8*)(wt + (size_t)idx * 8) = v;
}

extern "C" void kernel_launch(void* const* d_in, const int* in_sizes, int n_in,
                              void* d_out, int out_size, void* d_ws, size_t ws_size,
                              hipStream_t stream)
{
  const float* x = (const float*)d_in[0];
  const float* Wf1_0 = (const float*)d_in[1];
  const float* bf1_0 = (const float*)d_in[2];
  const float* Wf2_0 = (const float*)d_in[3];
  const float* bf2_0 = (const float*)d_in[4];
  const float* Wta_0 = (const float*)d_in[5];
  const float* bta_0 = (const float*)d_in[6];
  const float* Wtb_0 = (const float*)d_in[7];
  const float* btb_0 = (const float*)d_in[8];
  const int*   msk_0 = (const int*)  d_in[9];
  const float* Wf1_1 = (const float*)d_in[10];
  const float* bf1_1 = (const float*)d_in[11];
  const float* Wf2_1 = (const float*)d_in[12];
  const float* bf2_1 = (const float*)d_in[13];
  const float* Wta_1 = (const float*)d_in[14];
  const float* bta_1 = (const float*)d_in[15];
  const float* Wtb_1 = (const float*)d_in[16];
  const float* btb_1 = (const float*)d_in[17];
  const int*   msk_1 = (const int*)  d_in[18];
  const float* Wf1_2 = (const float*)d_in[19];
  const float* bf1_2 = (const float*)d_in[20];
  const float* Wf2_2 = (const float*)d_in[21];
  const float* bf2_2 = (const float*)d_in[22];
  const float* Wta_2 = (const float*)d_in[23];
  const float* bta_2 = (const float*)d_in[24];
  const float* Wtb_2 = (const float*)d_in[25];
  const float* btb_2 = (const float*)d_in[26];
  const int*   msk_2 = (const int*)  d_in[27];

  char* ws = (char*)d_ws;
  _Float16* wt0 = (_Float16*)(ws + 0);        // 17*3*4*1024 = 208896
  _Float16* wt1 = (_Float16*)(ws + 208896);   // 12*9*4*1024 = 442368
  _Float16* wt2 = (_Float16*)(ws + 651264);   //  4*6*4*1024 =  98304

  pack_w<<<(17 * KS0 * 4 * 64 + 255) / 256, 256, 0, stream>>>(
      Wf1_0, Wf2_0, Wta_0, Wtb_0, bf1_0, bf2_0, bta_0, btb_0, msk_0, wt0, IN0, H0, KS0, 17);
  pack_w<<<(12 * KS1 * 4 * 64 + 255) / 256, 256, 0, stream>>>(
      Wf1_1, Wf2_1, Wta_1, Wtb_1, bf1_1, bf2_1, bta_1, btb_1, msk_1, wt1, H0, H1, KS1, 12);
  pack_w<<<( 4 * KS2 * 4 * 64 + 255) / 256, 256, 0, stream>>>(
      Wf1_2, Wf2_2, Wta_2, Wtb_2, bf1_2, bf2_2, bta_2, btb_2, msk_2, wt2, H1, H2, KS2, 4);

  cfc_fused<<<65536 / BM, 512, 0, stream>>>(x, wt0, wt1, wt2, (float*)d_out);
}